// Round 16
// baseline (413.166 us; speedup 1.0000x reference)
//
#include <hip/hip_runtime.h>
#include <math.h>

typedef __bf16 bf16;
typedef __bf16 bf16x8 __attribute__((ext_vector_type(8)));
typedef float  f32x4  __attribute__((ext_vector_type(4)));

// Problem constants
constexpr int B_   = 32;
constexpr int T_   = 256;
constexpr int V_   = 25;
constexpr int NTV  = T_ * V_;                 // 6400
constexpr long long TENSOR = (long long)B_ * 128 * NTV; // 26,214,400 elems

// ws layout (float slots).
constexpr long long ACC_OFF  = 0;                        // fp32 [32][6400][128]
constexpr long long XGT_OFF  = 0;                        // bf16 [32][6400][128]
constexpr long long WRB3_OFF = XGT_OFF + TENSOR / 2;     // bf16 conv weights (lane-major)
constexpr long long WRB5_OFF = WRB3_OFF + 128 * 128 * 3 / 2;
constexpr long long WRB7_OFF = WRB5_OFF + 128 * 128 * 5 / 2;
constexpr long long WGB_OFF  = WRB7_OFF + 128 * 128 * 7 / 2;  // bf16 wgbl lane-major (16 KB)
constexpr long long Y0_OFF   = ACC_OFF + TENSOR;         // bf16 x3 [32][6400][128]
constexpr long long Y1_OFF   = Y0_OFF + TENSOR / 2;
constexpr long long Y2_OFF   = Y1_OFF + TENSOR / 2;
constexpr long long XT_OFF   = Y2_OFF + TENSOR / 2;      // bf16 [32][6400][64]
constexpr long long ABIG_OFF = XT_OFF + TENSOR / 4;      // bf16 [32][8][14][64][8] lane-major
constexpr long long BIAS_OFF = ABIG_OFF + (32LL * 128 * 448) / 2; // f32 [32][128]
constexpr long long STATS_OFF = BIAS_OFF + 4096;         // 5 x 512 floats (finalized mu/rstd)
// per-block stat partials (plain stores, no atomics)
constexpr long long P1_OFF = STATS_OFF + 2560;           // [32][256][16]
constexpr long long P2_OFF = P1_OFF + 32LL * 256 * 16;   // 3 x [32][50][16]
constexpr long long P3_OFF = P2_OFF + 3LL * 32 * 50 * 16;// [32][200][16]

__device__ __forceinline__ float bflo(unsigned u) { return __builtin_bit_cast(float, u << 16); }
__device__ __forceinline__ float bfhi(unsigned u) { return __builtin_bit_cast(float, u & 0xffff0000u); }
__device__ __forceinline__ unsigned packbf2(float a, float b) {
    unsigned short ua = __builtin_bit_cast(unsigned short, (bf16)a);
    unsigned short ub = __builtin_bit_cast(unsigned short, (bf16)b);
    return (unsigned)ua | ((unsigned)ub << 16);
}

// ---------------- merged prep: 3 conv-weight repacks + wgbl repack ----------------
constexpr int N3 = 128 * 128 * 3;
constexpr int N5 = 128 * 128 * 5;
constexpr int N7 = 128 * 128 * 7;
constexpr int NW = N3 + N5 + N7;          // 245760
constexpr int PREP_TOT = NW + 8192;       // 253952

__global__ void prep_kernel(const float* __restrict__ w3, const float* __restrict__ w5,
                            const float* __restrict__ w7, const float* __restrict__ wg,
                            bf16* __restrict__ wr3, bf16* __restrict__ wr5, bf16* __restrict__ wr7,
                            bf16* __restrict__ wgbl) {
    int idx = blockIdx.x * 256 + threadIdx.x;
    if (idx < NW) {
        const float* w; bf16* wr; int K; int i = idx;
        if (i < N3)           { w = w3; wr = wr3; K = 3; }
        else if (i < N3 + N5) { i -= N3; w = w5; wr = wr5; K = 5; }
        else                  { i -= N3 + N5; w = w7; wr = wr7; K = 7; }
        int e = i & 7, lane = (i >> 3) & 63, rem = i >> 9;
        int cb = rem & 3, rem2 = rem >> 2;
        int dt = rem2 % K, cb_co = rem2 / K;
        int l15 = lane & 15, l4 = lane >> 4;
        int co = cb_co * 16 + l15;
        int ci = cb * 32 + l4 * 8 + e;
        wr[i] = (bf16)w[(co * 128 + ci) * K + dt];
    } else if (idx < PREP_TOT) {
        int i = idx - NW;
        int e = i & 7, lane = (i >> 3) & 63, q = i >> 9;
        int cb_co = q >> 1, cb = q & 1;
        int co = cb_co * 16 + (lane & 15);
        int ci = cb * 32 + (lane >> 4) * 8 + e;
        int h = co >> 5, d = co & 31;
        wgbl[i] = (bf16)wg[h * 2048 + ci * 32 + d];
    }
}

// ---------------- parallel reduce: per-block partials -> finalized mu/rstd ----------------
__global__ __launch_bounds__(256) void reduce_stats_kernel(const float* __restrict__ pbuf, int ntiles,
                                                           float* __restrict__ st,
                                                           long long pstride, int sstride) {
    __shared__ float s_v[256];
    int b = blockIdx.x, seg = blockIdx.y, t = threadIdx.x;
    const float* p = pbuf + (long long)seg * pstride + ((long long)b * ntiles) * 16;
    int slot = t & 15;
    int chunk = t >> 4;
    float acc = 0.f;
    for (int i = chunk; i < ntiles; i += 16)
        acc += p[i * 16 + slot];
    s_v[t] = acc;
    __syncthreads();
    for (int off = 8; off > 0; off >>= 1) {
        if (chunk < off) s_v[t] += s_v[t + off * 16];
        __syncthreads();
    }
    if (t < 8) {
        float s = s_v[t], q = s_v[t + 8];
        float mu = s * (1.f / 102400.f);
        float var = q * (1.f / 102400.f) - mu * mu;
        float* so = st + (long long)seg * sstride;
        so[b * 8 + t] = mu;
        so[256 + b * 8 + t] = rsqrtf(var + 1e-5f);
    }
}

// ---------------- fused GAT: reads x directly; emits xgt + xt + gn1 partials ----------------
__global__ __launch_bounds__(256) void gat_fused_kernel(const float* __restrict__ x,
                                                        const bf16* __restrict__ wgbl,
                                                        const float* __restrict__ adj,
                                                        const float* __restrict__ ag,
                                                        bf16* __restrict__ xgt,
                                                        bf16* __restrict__ xt,
                                                        float* __restrict__ p1) {
    __shared__ __align__(16) bf16 s_xt[32 * 64];
    __shared__ float s_wh[25 * 132];
    __shared__ float s_att[100 * 28];
    __shared__ float s_e1[100], s_e2[100];
    __shared__ float s_adj[625];
    __shared__ float s_rs[256], s_rq[256];

    int tile = blockIdx.x, b = blockIdx.y, tid = threadIdx.x;
    long long nb0 = (long long)b * NTV + tile * 25;

    {
        int r = tid >> 3, ch = tid & 7;
        uint4 o = {0u, 0u, 0u, 0u};
        if (r < 25) {
            const float* xp = x + ((long long)(b * 64 + ch * 8)) * NTV + tile * 25 + r;
            float v[8];
#pragma unroll
            for (int e = 0; e < 8; ++e) v[e] = xp[(long long)e * NTV];
            o.x = packbf2(v[0], v[1]);
            o.y = packbf2(v[2], v[3]);
            o.z = packbf2(v[4], v[5]);
            o.w = packbf2(v[6], v[7]);
        }
        *reinterpret_cast<uint4*>(s_xt + r * 64 + ((ch ^ (r & 7)) << 3)) = o;
    }
    for (int o = tid; o < 625; o += 256) s_adj[o] = adj[o];
    __syncthreads();

    if (tid < 200) {
        int r = tid >> 3, ch = tid & 7;
        uint4 v = *reinterpret_cast<const uint4*>(s_xt + r * 64 + (ch ^ (r & 7)) * 8);
        *reinterpret_cast<uint4*>(xt + (nb0 + r) * 64 + ch * 8) = v;
    }

    int wid = tid >> 6, lane = tid & 63, l15 = lane & 15, l4 = lane >> 4;
    int co0 = wid * 32;

    f32x4 acc[2][2];
#pragma unroll
    for (int m = 0; m < 2; ++m)
#pragma unroll
        for (int ns = 0; ns < 2; ++ns) acc[m][ns] = f32x4{0.f, 0.f, 0.f, 0.f};
#pragma unroll
    for (int cb = 0; cb < 2; ++cb) {
        bf16x8 a0 = *(const bf16x8*)(wgbl + (((wid * 2 + 0) * 2 + cb) * 64 + lane) * 8);
        bf16x8 a1 = *(const bf16x8*)(wgbl + (((wid * 2 + 1) * 2 + cb) * 64 + lane) * 8);
#pragma unroll
        for (int ns = 0; ns < 2; ++ns) {
            int r = ns * 16 + l15;
            int chunk = (cb * 4 + l4) ^ (r & 7);
            bf16x8 bv = *(const bf16x8*)(s_xt + r * 64 + chunk * 8);
            acc[0][ns] = __builtin_amdgcn_mfma_f32_16x16x32_bf16(a0, bv, acc[0][ns], 0, 0, 0);
            acc[1][ns] = __builtin_amdgcn_mfma_f32_16x16x32_bf16(a1, bv, acc[1][ns], 0, 0, 0);
        }
    }

    float4 a1v[2], a2v[2];
#pragma unroll
    for (int m = 0; m < 2; ++m) {
        a1v[m] = *reinterpret_cast<const float4*>(ag + wid * 64 + m * 16 + l4 * 4);
        a2v[m] = *reinterpret_cast<const float4*>(ag + wid * 64 + 32 + m * 16 + l4 * 4);
    }
#pragma unroll
    for (int ns = 0; ns < 2; ++ns) {
        int r = ns * 16 + l15;
        if (r < 25) {
            *reinterpret_cast<float4*>(&s_wh[r * 132 + co0 + l4 * 4]) =
                float4{acc[0][ns][0], acc[0][ns][1], acc[0][ns][2], acc[0][ns][3]};
            *reinterpret_cast<float4*>(&s_wh[r * 132 + co0 + 16 + l4 * 4]) =
                float4{acc[1][ns][0], acc[1][ns][1], acc[1][ns][2], acc[1][ns][3]};
        }
        float pe1 = acc[0][ns][0] * a1v[0].x + acc[0][ns][1] * a1v[0].y
                  + acc[0][ns][2] * a1v[0].z + acc[0][ns][3] * a1v[0].w
                  + acc[1][ns][0] * a1v[1].x + acc[1][ns][1] * a1v[1].y
                  + acc[1][ns][2] * a1v[1].z + acc[1][ns][3] * a1v[1].w;
        float pe2 = acc[0][ns][0] * a2v[0].x + acc[0][ns][1] * a2v[0].y
                  + acc[0][ns][2] * a2v[0].z + acc[0][ns][3] * a2v[0].w
                  + acc[1][ns][0] * a2v[1].x + acc[1][ns][1] * a2v[1].y
                  + acc[1][ns][2] * a2v[1].z + acc[1][ns][3] * a2v[1].w;
        pe1 += __shfl_xor(pe1, 16); pe1 += __shfl_xor(pe1, 32);
        pe2 += __shfl_xor(pe2, 16); pe2 += __shfl_xor(pe2, 32);
        if (l4 == 0 && r < 25) { s_e1[r * 4 + wid] = pe1; s_e2[r * 4 + wid] = pe2; }
    }
    __syncthreads();

    if (tid < 100) {
        int h = tid / 25, i = tid - h * 25;
        float ei = s_e1[i * 4 + h];
        float ev[25];
        float mx = -3.4e38f;
#pragma unroll
        for (int j = 0; j < 25; j++) {
            float e = ei + s_e2[j * 4 + h];
            e = e > 0.f ? e : 0.2f * e;
            e = (s_adj[i * 25 + j] > 0.f) ? e : -9.0e15f;
            ev[j] = e;
            mx = fmaxf(mx, e);
        }
        float sum = 0.f;
#pragma unroll
        for (int j = 0; j < 25; j++) { float p = __expf(ev[j] - mx); ev[j] = p; sum += p; }
        float inv = 1.f / sum;
        int row = (h * 25 + i) * 28;
#pragma unroll
        for (int j = 0; j < 25; j++) s_att[row + j] = ev[j] * inv;
        s_att[row + 25] = 0.f; s_att[row + 26] = 0.f; s_att[row + 27] = 0.f;
    }
    __syncthreads();

    int hd = tid & 127, vh = tid >> 7;
    int v0 = vh * 13, nv = vh ? 12 : 13;
    int h = hd >> 5;
    float whr[28];
#pragma unroll
    for (int j = 0; j < 25; ++j) whr[j] = s_wh[j * 132 + hd];
    whr[25] = 0.f; whr[26] = 0.f; whr[27] = 0.f;
    float accp[13];
#pragma unroll
    for (int i = 0; i < 13; i++) accp[i] = 0.f;
#pragma unroll
    for (int i = 0; i < 13; i++) {
        int row = (h * 25 + v0 + i) * 28;
#pragma unroll
        for (int j4 = 0; j4 < 7; ++j4) {
            float4 a4 = *reinterpret_cast<const float4*>(&s_att[row + j4 * 4]);
            accp[i] += a4.x * whr[j4 * 4] + a4.y * whr[j4 * 4 + 1]
                     + a4.z * whr[j4 * 4 + 2] + a4.w * whr[j4 * 4 + 3];
        }
    }

    // epilogue: elu (fast exp) -> bf16 -> xgt; gn1 per-block partials
    float ssum = 0.f, qsum = 0.f;
    for (int i = 0; i < nv; i++) {
        float val = accp[i];
        val = val > 0.f ? val : (__expf(val) - 1.f);
        bf16 bv = (bf16)val;
        xgt[(nb0 + v0 + i) * 128 + hd] = bv;
        float f = (float)bv;
        ssum += f; qsum += f * f;
    }
    s_rs[tid] = ssum; s_rq[tid] = qsum;
    __syncthreads();
    if (tid < 8) {
        float ss = 0.f, qq = 0.f;
#pragma unroll
        for (int k = 0; k < 16; ++k) {
            int ch = tid * 16 + k;
            ss += s_rs[ch] + s_rs[ch + 128];
            qq += s_rq[ch] + s_rq[ch + 128];
        }
        float* pp = p1 + ((long long)(b * 256 + tile)) * 16;
        pp[tid] = ss;
        pp[8 + tid] = qq;
    }
}

// ---------------- conv body (64co x 64n wave tiles: ds_read:MFMA = 1:4) ----------------
template <int K>
__device__ __forceinline__ void conv_body(bf16* __restrict__ s_h,
                                          float* __restrict__ s_sc, float* __restrict__ s_bc,
                                          float* __restrict__ s_ps, float* __restrict__ s_pq,
                                          const bf16* __restrict__ xgt,
                                          const bf16* __restrict__ wr,
                                          const float* __restrict__ bb,
                                          const float* __restrict__ g1,
                                          const float* __restrict__ b1,
                                          const float* __restrict__ stats1,
                                          bf16* __restrict__ y,
                                          float* __restrict__ p2,
                                          int tile, int b, int tid) {
    constexpr int P = (K - 1) / 2;
    constexpr int ROWS = 128 + (K - 1) * 25;
    constexpr int NCH = ROWS * 16;
    constexpr int ITERS = (NCH + 255) / 256;

    int n0 = tile * 128;
    if (tid < 128) {
        int g = tid >> 4;
        float mu = stats1[b * 8 + g], rs = stats1[256 + b * 8 + g];
        float sc = rs * g1[tid];
        s_sc[tid] = sc;
        s_bc[tid] = b1[tid] - mu * sc;
    }
    __syncthreads();

    int ch = tid & 15;
    float sc8[8], bc8[8];
#pragma unroll
    for (int j = 0; j < 8; ++j) { sc8[j] = s_sc[ch * 8 + j]; bc8[j] = s_bc[ch * 8 + j]; }

    int nb = b * NTV;
    for (int it = 0; it < ITERS; ++it) {
        int flat = it * 256 + tid;
        if (flat < NCH) {
            int r = flat >> 4;
            int n = n0 - P * 25 + r;
            uint4 v = {0u, 0u, 0u, 0u};
            if ((unsigned)n < (unsigned)NTV)
                v = *reinterpret_cast<const uint4*>(xgt + ((long long)(nb + n)) * 128 + ch * 8);
            unsigned w[4] = {v.x, v.y, v.z, v.w};
            uint4 o;
            unsigned* op = &o.x;
#pragma unroll
            for (int p = 0; p < 4; ++p) {
                float f0 = fmaxf(bflo(w[p]) * sc8[2 * p] + bc8[2 * p], 0.f);
                float f1 = fmaxf(bfhi(w[p]) * sc8[2 * p + 1] + bc8[2 * p + 1], 0.f);
                op[p] = packbf2(f0, f1);
            }
            *reinterpret_cast<uint4*>(s_h + r * 128 + (ch ^ (r & 15)) * 8) = o;
        }
    }
    __syncthreads();

    int wid = tid >> 6, lane = tid & 63, l15 = lane & 15, l4 = lane >> 4;
    int coh = wid >> 1;            // co-half (64 co)
    int rh  = wid & 1;             // row-half (64 rows)
    int co0 = coh * 64;
    int r0  = rh * 64;
    f32x4 acc[4][4];
#pragma unroll
    for (int m = 0; m < 4; ++m)
#pragma unroll
        for (int ns = 0; ns < 4; ++ns) acc[m][ns] = f32x4{0.f, 0.f, 0.f, 0.f};

    const bf16* wrA = wr + lane * 8;   // lane-major A
    for (int dt = 0; dt < K; ++dt) {
#pragma unroll
        for (int cb = 0; cb < 4; ++cb) {
            bf16x8 a[4];
#pragma unroll
            for (int m = 0; m < 4; ++m)
                a[m] = *(const bf16x8*)(wrA + (((coh * 4 + m) * K + dt) * 4 + cb) * 512);
#pragma unroll
            for (int ns = 0; ns < 4; ++ns) {
                int r = r0 + ns * 16 + l15 + dt * 25;
                int chunk = (cb * 4 + l4) ^ (r & 15);
                bf16x8 bv = *(const bf16x8*)(s_h + r * 128 + chunk * 8);
#pragma unroll
                for (int m = 0; m < 4; ++m)
                    acc[m][ns] = __builtin_amdgcn_mfma_f32_16x16x32_bf16(a[m], bv, acc[m][ns], 0, 0, 0);
            }
        }
    }
    __syncthreads();   // s_h -> s_y reuse

    bf16* sy = s_h;
    float bias[4][4];
#pragma unroll
    for (int m = 0; m < 4; ++m)
#pragma unroll
        for (int rr = 0; rr < 4; ++rr) bias[m][rr] = bb[co0 + m * 16 + l4 * 4 + rr];
    float ssum[4] = {0.f, 0.f, 0.f, 0.f}, qsum[4] = {0.f, 0.f, 0.f, 0.f};
#pragma unroll
    for (int m = 0; m < 4; ++m)
#pragma unroll
        for (int ns = 0; ns < 4; ++ns) {
            int nl = r0 + ns * 16 + l15;
            uint2 pk;
            pk.x = packbf2(acc[m][ns][0] + bias[m][0], acc[m][ns][1] + bias[m][1]);
            pk.y = packbf2(acc[m][ns][2] + bias[m][2], acc[m][ns][3] + bias[m][3]);
            float f0 = bflo(pk.x), f1 = bfhi(pk.x), f2 = bflo(pk.y), f3 = bfhi(pk.y);
            ssum[m] += f0 + f1 + f2 + f3;
            qsum[m] += f0 * f0 + f1 * f1 + f2 * f2 + f3 * f3;
            *reinterpret_cast<uint2*>(sy + nl * 136 + co0 + m * 16 + l4 * 4) = pk;
        }
    // gn2 partials: group g = coh*4 + m; two row-half waves contribute, combined below
#pragma unroll
    for (int m = 0; m < 4; ++m) {
        float s = ssum[m], q = qsum[m];
#pragma unroll
        for (int off = 32; off > 0; off >>= 1) { s += __shfl_xor(s, off); q += __shfl_xor(q, off); }
        if (lane == 0) { s_ps[wid * 4 + m] = s; s_pq[wid * 4 + m] = q; }
    }
    __syncthreads();
    if (tid < 8) {
        int coh_g = tid >> 2, m_g = tid & 3;
        float s = s_ps[(coh_g * 2 + 0) * 4 + m_g] + s_ps[(coh_g * 2 + 1) * 4 + m_g];
        float q = s_pq[(coh_g * 2 + 0) * 4 + m_g] + s_pq[(coh_g * 2 + 1) * 4 + m_g];
        float* pp = p2 + ((long long)(b * 50 + tile)) * 16;
        pp[tid] = s;
        pp[8 + tid] = q;
    }
#pragma unroll
    for (int it = 0; it < 8; ++it) {
        int flat = it * 256 + tid;
        int nl = flat >> 4, c2 = flat & 15;
        uint4 v = *reinterpret_cast<const uint4*>(sy + nl * 136 + c2 * 8);
        *reinterpret_cast<uint4*>(y + ((long long)(nb + n0 + nl)) * 128 + c2 * 8) = v;
    }
}

// ---------------- merged conv launch: blockIdx.z selects branch ----------------
__global__ __launch_bounds__(256) void conv_all_kernel(const bf16* __restrict__ xgt,
                                                       const bf16* __restrict__ wr3,
                                                       const bf16* __restrict__ wr5,
                                                       const bf16* __restrict__ wr7,
                                                       const float* __restrict__ bb3,
                                                       const float* __restrict__ bb5,
                                                       const float* __restrict__ bb7,
                                                       const float* __restrict__ g13,
                                                       const float* __restrict__ g15,
                                                       const float* __restrict__ g17,
                                                       const float* __restrict__ b13,
                                                       const float* __restrict__ b15,
                                                       const float* __restrict__ b17,
                                                       const float* __restrict__ stats1,
                                                       bf16* __restrict__ y0,
                                                       bf16* __restrict__ y1,
                                                       bf16* __restrict__ y2,
                                                       float* __restrict__ p2) {
    __shared__ bf16 s_h[278 * 128];     // sized for K=7 window
    __shared__ float s_sc[128], s_bc[128];
    __shared__ float s_ps[16], s_pq[16];
    int tile = blockIdx.x, b = blockIdx.y, tid = threadIdx.x;
    switch (blockIdx.z) {
        case 0:
            conv_body<3>(s_h, s_sc, s_bc, s_ps, s_pq, xgt, wr3, bb3, g13, b13,
                         stats1, y0, p2, tile, b, tid);
            break;
        case 1:
            conv_body<5>(s_h, s_sc, s_bc, s_ps, s_pq, xgt, wr5, bb5, g15, b15,
                         stats1, y1, p2 + 25600, tile, b, tid);
            break;
        default:
            conv_body<7>(s_h, s_sc, s_bc, s_ps, s_pq, xgt, wr7, bb7, g17, b17,
                         stats1, y2, p2 + 51200, tile, b, tid);
            break;
    }
}

// ---------------- fold gn2 into fusion weights: grid (32 b, 8 cb_co) ----------------
__global__ __launch_bounds__(256) void fold_kernel(const float* __restrict__ fus_w, const float* __restrict__ fus_b,
                                                   const float* __restrict__ res_w, const float* __restrict__ res_b,
                                                   const float* __restrict__ g20, const float* __restrict__ b20,
                                                   const float* __restrict__ g21, const float* __restrict__ b21,
                                                   const float* __restrict__ g22, const float* __restrict__ b22,
                                                   const float* __restrict__ st0, const float* __restrict__ st1,
                                                   const float* __restrict__ st2,
                                                   bf16* __restrict__ Abig, float* __restrict__ biasb) {
    __shared__ float s_sc[384], s_bc[384];
    int b = blockIdx.x, cb_co = blockIdx.y, tid = threadIdx.x;
    int co0 = cb_co * 16;
    for (int o = tid; o < 384; o += 256) {
        int k = o >> 7, cc = o & 127, g = cc >> 4;
        const float* st = (k == 0) ? st0 : (k == 1) ? st1 : st2;
        const float* gg = (k == 0) ? g20 : (k == 1) ? g21 : g22;
        const float* b2 = (k == 0) ? b20 : (k == 1) ? b21 : b22;
        float mu = st[b * 8 + g], rs = st[256 + b * 8 + g];
        float sc = rs * gg[cc];
        s_sc[o] = sc;
        s_bc[o] = b2[cc] - mu * sc;
    }
    __syncthreads();

    bf16* abase = Abig + ((long long)(b * 8 + cb_co)) * 14 * 512;
#pragma unroll 1
    for (int it = 0; it < 28; ++it) {
        int o = it * 256 + tid;
        int e = o & 7;
        int lane = (o >> 3) & 63;
        int ks = o >> 9;
        int l15 = lane & 15, l4 = lane >> 4;
        int co = co0 + l15;
        int j = ks * 32 + l4 * 8 + e;
        float val = (j < 384) ? fus_w[co * 384 + j] * s_sc[j] : res_w[co * 64 + (j - 384)];
        abase[o] = (bf16)val;
    }

    int co_l = tid >> 4, part = tid & 15;
    int co = co0 + co_l;
    float s = 0.f;
#pragma unroll
    for (int k = 0; k < 24; ++k) {
        int j = part + k * 16;
        s += fus_w[co * 384 + j] * s_bc[j];
    }
#pragma unroll
    for (int off = 1; off < 16; off <<= 1) s += __shfl_xor(s, off);
    if (part == 0)
        biasb[b * 128 + co] = fus_b[co] + res_b[co] + s;
}

// ---------------- fused output GEMM (32-row tiles) + gn3 per-block partials ----------------
__global__ __launch_bounds__(256) void fuse_mfma_kernel(const bf16* __restrict__ y0, const bf16* __restrict__ y1,
                                                        const bf16* __restrict__ y2, const bf16* __restrict__ xt,
                                                        const bf16* __restrict__ Abig, const float* __restrict__ biasb,
                                                        float* __restrict__ accf, float* __restrict__ p3) {
    __shared__ __align__(16) bf16 s_b[32 * 448];
    __shared__ float s_ps[8], s_pq[8];
    int tile = blockIdx.x, b = blockIdx.y, tid = threadIdx.x;
    int n0 = tile * 32;

    int c = tid % 56;
    int roff = tid / 56;
    bool act = tid < 224;
    const bf16* src;
    int stride;
    if (c < 48) {
        src = (c < 16 ? y0 : (c < 32 ? y1 : y2)) + (c & 15) * 8;
        stride = 128;
    } else {
        src = xt + (c - 48) * 8;
        stride = 64;
    }
    src += (long long)(b * NTV + n0) * stride;
    if (act) {
#pragma unroll
        for (int it = 0; it < 8; ++it) {
            int r = it * 4 + roff;
            uint4 v = *reinterpret_cast<const uint4*>(src + (long long)r * stride);
            *reinterpret_cast<uint4*>(s_b + r * 448 + (c ^ (r & 7)) * 8) = v;
        }
    }
    __syncthreads();

    int wid = tid >> 6, lane = tid & 63, l15 = lane & 15, l4 = lane >> 4;
    int co0 = wid * 32;
    f32x4 acc[2][2];
#pragma unroll
    for (int m = 0; m < 2; ++m)
#pragma unroll
        for (int ns = 0; ns < 2; ++ns) acc[m][ns] = f32x4{0.f, 0.f, 0.f, 0.f};

    const bf16* abase = Abig + (((long long)(b * 8 + wid * 2)) * 14 * 64 + lane) * 8;
#pragma unroll
    for (int ks = 0; ks < 14; ++ks) {
        bf16x8 a0 = *(const bf16x8*)(abase + ks * 512);
        bf16x8 a1 = *(const bf16x8*)(abase + 14 * 512 + ks * 512);
        int ci = ks * 4 + l4;
#pragma unroll
        for (int ns = 0; ns < 2; ++ns) {
            int r = ns * 16 + l15;
            bf16x8 bv = *(const bf16x8*)(s_b + r * 448 + (ci ^ (r & 7)) * 8);
            acc[0][ns] = __builtin_amdgcn_mfma_f32_16x16x32_bf16(a0, bv, acc[0][ns], 0, 0, 0);
            acc[1][ns] = __builtin_amdgcn_mfma_f32_16x16x32_bf16(a1, bv, acc[1][ns], 0, 0, 0);
        }
    }

    float bias[2][4];
#pragma unroll
    for (int m = 0; m < 2; ++m)
#pragma unroll
        for (int rr = 0; rr < 4; ++rr) bias[m][rr] = biasb[b * 128 + co0 + m * 16 + l4 * 4 + rr];

    __syncthreads();
    float* s_yf = reinterpret_cast<float*>(s_b);
    float ssum[2] = {0.f, 0.f}, qsum[2] = {0.f, 0.f};
#pragma unroll
    for (int m = 0; m < 2; ++m)
#pragma unroll
        for (int ns = 0; ns < 2; ++ns) {
            int nl = ns * 16 + l15;
            float4 val;
            val.x = acc[m][ns][0] + bias[m][0];
            val.y = acc[m][ns][1] + bias[m][1];
            val.z = acc[m][ns][2] + bias[m][2];
            val.w = acc[m][ns][3] + bias[m][3];
            float r0 = fmaxf(val.x, 0.f), r1 = fmaxf(val.y, 0.f);
            float r2 = fmaxf(val.z, 0.f), r3 = fmaxf(val.w, 0.f);
            ssum[m] += r0 + r1 + r2 + r3;
            qsum[m] += r0 * r0 + r1 * r1 + r2 * r2 + r3 * r3;
            *reinterpret_cast<float4*>(s_yf + nl * 136 + co0 + m * 16 + l4 * 4) = val;
        }
#pragma unroll
    for (int m = 0; m < 2; ++m) {
        float s = ssum[m], q = qsum[m];
#pragma unroll
        for (int off = 32; off > 0; off >>= 1) { s += __shfl_xor(s, off); q += __shfl_xor(q, off); }
        if (lane == 0) { s_ps[wid * 2 + m] = s; s_pq[wid * 2 + m] = q; }
    }
    __syncthreads();
    if (tid < 8) {
        float* pp = p3 + ((long long)(b * 200 + tile)) * 16;
        pp[tid] = s_ps[tid];
        pp[8 + tid] = s_pq[tid];
    }
#pragma unroll
    for (int it = 0; it < 4; ++it) {
        int flat = it * 256 + tid;
        int nl = flat >> 5, cq = flat & 31;
        float4 v = *reinterpret_cast<const float4*>(s_yf + nl * 136 + cq * 4);
        *reinterpret_cast<float4*>(accf + ((long long)(b * NTV + n0 + nl)) * 128 + cq * 4) = v;
    }
}

// ---------------- final: out = gn3(relu(acc fp32)), transpose to [b][c][n] fp32 ----------------
__global__ __launch_bounds__(256) void final_kernel(const float* __restrict__ accf,
                                                    const float* __restrict__ stats3,
                                                    const float* __restrict__ ng,
                                                    const float* __restrict__ nb,
                                                    float* __restrict__ out) {
    __shared__ float s_o[128 * 72];
    __shared__ float s_sc[128], s_bc[128];
    int tile = blockIdx.x, b = blockIdx.y, tid = threadIdx.x;
    int n0 = tile * 64;
    if (tid < 128) {
        int g = tid >> 4;
        float mu = stats3[b * 8 + g], rs = stats3[256 + b * 8 + g];
        float sv = rs * ng[tid];
        s_sc[tid] = sv;
        s_bc[tid] = nb[tid] - mu * sv;
    }
    __syncthreads();
#pragma unroll
    for (int it = 0; it < 8; ++it) {
        int flat = it * 256 + tid;
        int r = flat >> 5, cq = flat & 31;
        float4 v = *reinterpret_cast<const float4*>(accf + ((long long)(b * NTV + n0 + r)) * 128 + cq * 4);
        float f[4] = {v.x, v.y, v.z, v.w};
#pragma unroll
        for (int p = 0; p < 4; ++p) {
            int ci = cq * 4 + p;
            s_o[ci * 72 + r] = fmaxf(f[p], 0.f) * s_sc[ci] + s_bc[ci];
        }
    }
    __syncthreads();
#pragma unroll
    for (int it = 0; it < 8; ++it) {
        int flat = it * 256 + tid;
        int ci = flat >> 4, q = flat & 15;
        float4 v = *reinterpret_cast<const float4*>(s_o + ci * 72 + q * 4);
        *reinterpret_cast<float4*>(out + ((long long)(b * 128 + ci)) * NTV + n0 + q * 4) = v;
    }
}

extern "C" void kernel_launch(void* const* d_in, const int* in_sizes, int n_in,
                              void* d_out, int out_size, void* d_ws, size_t ws_size,
                              hipStream_t stream) {
    const float* x      = (const float*)d_in[0];
    const float* adj    = (const float*)d_in[1];
    const float* w_gat  = (const float*)d_in[2];
    const float* a_gat  = (const float*)d_in[3];
    const float* fus_w  = (const float*)d_in[4];
    const float* fus_b  = (const float*)d_in[5];
    const float* res_w  = (const float*)d_in[6];
    const float* res_b  = (const float*)d_in[7];
    const float* norm_g = (const float*)d_in[8];
    const float* norm_b = (const float*)d_in[9];
    const float* tg1[3], *tb1[3], *tw[3], *tbb[3], *tg2[3], *tb2[3];
    for (int i = 0; i < 3; i++) {
        tg1[i] = (const float*)d_in[10 + 6 * i + 0];
        tb1[i] = (const float*)d_in[10 + 6 * i + 1];
        tw[i]  = (const float*)d_in[10 + 6 * i + 2];
        tbb[i] = (const float*)d_in[10 + 6 * i + 3];
        tg2[i] = (const float*)d_in[10 + 6 * i + 4];
        tb2[i] = (const float*)d_in[10 + 6 * i + 5];
    }

    float* ws = (float*)d_ws;
    float* accf  = ws + ACC_OFF;                    // fp32, aliases xgt/wrb/wgbl (dead by fuse)
    bf16* xgt    = (bf16*)(ws + XGT_OFF);
    bf16* wrb[3] = { (bf16*)(ws + WRB3_OFF), (bf16*)(ws + WRB5_OFF), (bf16*)(ws + WRB7_OFF) };
    bf16* wgbl   = (bf16*)(ws + WGB_OFF);
    bf16* yb[3]  = { (bf16*)(ws + Y0_OFF), (bf16*)(ws + Y1_OFF), (bf16*)(ws + Y2_OFF) };
    bf16* xt     = (bf16*)(ws + XT_OFF);
    bf16* Abig   = (bf16*)(ws + ABIG_OFF);
    float* biasb = ws + BIAS_OFF;
    float* S1    = ws + STATS_OFF;
    float* S2    = S1 + 512;
    float* S3    = S1 + 2048;
    float* P1    = ws + P1_OFF;
    float* P2    = ws + P2_OFF;   // 3 x [32][50][16]
    float* P3    = ws + P3_OFF;   // [32][200][16]

    prep_kernel<<<(PREP_TOT + 255) / 256, 256, 0, stream>>>(tw[0], tw[1], tw[2], w_gat,
                                                            wrb[0], wrb[1], wrb[2], wgbl);

    dim3 g64(100, 32), gconv(50, 32, 3), g32f(200, 32), ggat(256, 32);

    // fused GAT (reads x; emits xgt, xt, gn1 partials)
    gat_fused_kernel<<<ggat, 256, 0, stream>>>(x, wgbl, adj, a_gat, xgt, xt, P1);
    reduce_stats_kernel<<<dim3(32, 1), 256, 0, stream>>>(P1, 256, S1, 0, 0);

    // all three convs in one launch (z = branch); gn2 per-block partials
    conv_all_kernel<<<gconv, 256, 0, stream>>>(xgt, wrb[0], wrb[1], wrb[2],
                                               tbb[0], tbb[1], tbb[2],
                                               tg1[0], tg1[1], tg1[2],
                                               tb1[0], tb1[1], tb1[2],
                                               S1, yb[0], yb[1], yb[2], P2);
    reduce_stats_kernel<<<dim3(32, 3), 256, 0, stream>>>(P2, 50, S2, 25600, 512);

    fold_kernel<<<dim3(32, 8), 256, 0, stream>>>(fus_w, fus_b, res_w, res_b,
                                                 tg2[0], tb2[0], tg2[1], tb2[1], tg2[2], tb2[2],
                                                 S2, S2 + 512, S2 + 1024, Abig, biasb);

    // fuse overwrites the xgt/wrb/wgbl region with fp32 acc; writes gn3 partials
    fuse_mfma_kernel<<<g32f, 256, 0, stream>>>(yb[0], yb[1], yb[2], xt, Abig, biasb, accf, P3);
    reduce_stats_kernel<<<dim3(32, 1), 256, 0, stream>>>(P3, 200, S3, 0, 0);

    final_kernel<<<g64, 256, 0, stream>>>(accf, S3, norm_g, norm_b, (float*)d_out);
}

// Round 17
// 374.318 us; speedup vs baseline: 1.1038x; 1.1038x over previous
//
#include <hip/hip_runtime.h>
#include <math.h>

typedef __bf16 bf16;
typedef __bf16 bf16x8 __attribute__((ext_vector_type(8)));
typedef float  f32x4  __attribute__((ext_vector_type(4)));

// Problem constants
constexpr int B_   = 32;
constexpr int T_   = 256;
constexpr int V_   = 25;
constexpr int NTV  = T_ * V_;                 // 6400
constexpr long long TENSOR = (long long)B_ * 128 * NTV; // 26,214,400 elems

// ws layout (float slots).
constexpr long long ACC_OFF  = 0;                        // fp32 [32][6400][128]
constexpr long long XGT_OFF  = 0;                        // bf16 [32][6400][128]
constexpr long long WRB3_OFF = XGT_OFF + TENSOR / 2;     // bf16 conv weights (lane-major)
constexpr long long WRB5_OFF = WRB3_OFF + 128 * 128 * 3 / 2;
constexpr long long WRB7_OFF = WRB5_OFF + 128 * 128 * 5 / 2;
constexpr long long WGB_OFF  = WRB7_OFF + 128 * 128 * 7 / 2;  // bf16 wgbl lane-major (16 KB)
constexpr long long Y0_OFF   = ACC_OFF + TENSOR;         // bf16 x3 [32][6400][128]
constexpr long long Y1_OFF   = Y0_OFF + TENSOR / 2;
constexpr long long Y2_OFF   = Y1_OFF + TENSOR / 2;
constexpr long long XT_OFF   = Y2_OFF + TENSOR / 2;      // bf16 [32][6400][64]
constexpr long long ABIG_OFF = XT_OFF + TENSOR / 4;      // bf16 [32][8][14][64][8] lane-major
constexpr long long BIAS_OFF = ABIG_OFF + (32LL * 128 * 448) / 2; // f32 [32][128]
constexpr long long STATS_OFF = BIAS_OFF + 4096;         // 5 x 512 floats (finalized mu/rstd)
// per-block stat partials (plain stores, no atomics)
constexpr long long P1_OFF = STATS_OFF + 2560;           // [32][256][16]
constexpr long long P2_OFF = P1_OFF + 32LL * 256 * 16;   // 3 x [32][50][16]
constexpr long long P3_OFF = P2_OFF + 3LL * 32 * 50 * 16;// [32][200][16]

__device__ __forceinline__ float bflo(unsigned u) { return __builtin_bit_cast(float, u << 16); }
__device__ __forceinline__ float bfhi(unsigned u) { return __builtin_bit_cast(float, u & 0xffff0000u); }
__device__ __forceinline__ unsigned packbf2(float a, float b) {
    unsigned short ua = __builtin_bit_cast(unsigned short, (bf16)a);
    unsigned short ub = __builtin_bit_cast(unsigned short, (bf16)b);
    return (unsigned)ua | ((unsigned)ub << 16);
}

// ---------------- merged prep: 3 conv-weight repacks + wgbl repack ----------------
constexpr int N3 = 128 * 128 * 3;
constexpr int N5 = 128 * 128 * 5;
constexpr int N7 = 128 * 128 * 7;
constexpr int NW = N3 + N5 + N7;          // 245760
constexpr int PREP_TOT = NW + 8192;       // 253952

__global__ void prep_kernel(const float* __restrict__ w3, const float* __restrict__ w5,
                            const float* __restrict__ w7, const float* __restrict__ wg,
                            bf16* __restrict__ wr3, bf16* __restrict__ wr5, bf16* __restrict__ wr7,
                            bf16* __restrict__ wgbl) {
    int idx = blockIdx.x * 256 + threadIdx.x;
    if (idx < NW) {
        const float* w; bf16* wr; int K; int i = idx;
        if (i < N3)           { w = w3; wr = wr3; K = 3; }
        else if (i < N3 + N5) { i -= N3; w = w5; wr = wr5; K = 5; }
        else                  { i -= N3 + N5; w = w7; wr = wr7; K = 7; }
        int e = i & 7, lane = (i >> 3) & 63, rem = i >> 9;
        int cb = rem & 3, rem2 = rem >> 2;
        int dt = rem2 % K, cb_co = rem2 / K;
        int l15 = lane & 15, l4 = lane >> 4;
        int co = cb_co * 16 + l15;
        int ci = cb * 32 + l4 * 8 + e;
        wr[i] = (bf16)w[(co * 128 + ci) * K + dt];
    } else if (idx < PREP_TOT) {
        int i = idx - NW;
        int e = i & 7, lane = (i >> 3) & 63, q = i >> 9;
        int cb_co = q >> 1, cb = q & 1;
        int co = cb_co * 16 + (lane & 15);
        int ci = cb * 32 + (lane >> 4) * 8 + e;
        int h = co >> 5, d = co & 31;
        wgbl[i] = (bf16)wg[h * 2048 + ci * 32 + d];
    }
}

// ---------------- parallel reduce: per-block partials -> finalized mu/rstd ----------------
__global__ __launch_bounds__(256) void reduce_stats_kernel(const float* __restrict__ pbuf, int ntiles,
                                                           float* __restrict__ st,
                                                           long long pstride, int sstride) {
    __shared__ float s_v[256];
    int b = blockIdx.x, seg = blockIdx.y, t = threadIdx.x;
    const float* p = pbuf + (long long)seg * pstride + ((long long)b * ntiles) * 16;
    int slot = t & 15;
    int chunk = t >> 4;
    float acc = 0.f;
    for (int i = chunk; i < ntiles; i += 16)
        acc += p[i * 16 + slot];
    s_v[t] = acc;
    __syncthreads();
    for (int off = 8; off > 0; off >>= 1) {
        if (chunk < off) s_v[t] += s_v[t + off * 16];
        __syncthreads();
    }
    if (t < 8) {
        float s = s_v[t], q = s_v[t + 8];
        float mu = s * (1.f / 102400.f);
        float var = q * (1.f / 102400.f) - mu * mu;
        float* so = st + (long long)seg * sstride;
        so[b * 8 + t] = mu;
        so[256 + b * 8 + t] = rsqrtf(var + 1e-5f);
    }
}

// ---------------- fused GAT: reads x directly; emits xgt + xt + gn1 partials ----------------
__global__ __launch_bounds__(256) void gat_fused_kernel(const float* __restrict__ x,
                                                        const bf16* __restrict__ wgbl,
                                                        const float* __restrict__ adj,
                                                        const float* __restrict__ ag,
                                                        bf16* __restrict__ xgt,
                                                        bf16* __restrict__ xt,
                                                        float* __restrict__ p1) {
    __shared__ __align__(16) bf16 s_xt[32 * 64];
    __shared__ float s_wh[25 * 132];
    __shared__ float s_att[100 * 28];
    __shared__ float s_e1[100], s_e2[100];
    __shared__ float s_adj[625];
    __shared__ float s_rs[256], s_rq[256];

    int tile = blockIdx.x, b = blockIdx.y, tid = threadIdx.x;
    long long nb0 = (long long)b * NTV + tile * 25;

    {
        int r = tid >> 3, ch = tid & 7;
        uint4 o = {0u, 0u, 0u, 0u};
        if (r < 25) {
            const float* xp = x + ((long long)(b * 64 + ch * 8)) * NTV + tile * 25 + r;
            float v[8];
#pragma unroll
            for (int e = 0; e < 8; ++e) v[e] = xp[(long long)e * NTV];
            o.x = packbf2(v[0], v[1]);
            o.y = packbf2(v[2], v[3]);
            o.z = packbf2(v[4], v[5]);
            o.w = packbf2(v[6], v[7]);
        }
        *reinterpret_cast<uint4*>(s_xt + r * 64 + ((ch ^ (r & 7)) << 3)) = o;
    }
    for (int o = tid; o < 625; o += 256) s_adj[o] = adj[o];
    __syncthreads();

    if (tid < 200) {
        int r = tid >> 3, ch = tid & 7;
        uint4 v = *reinterpret_cast<const uint4*>(s_xt + r * 64 + (ch ^ (r & 7)) * 8);
        *reinterpret_cast<uint4*>(xt + (nb0 + r) * 64 + ch * 8) = v;
    }

    int wid = tid >> 6, lane = tid & 63, l15 = lane & 15, l4 = lane >> 4;
    int co0 = wid * 32;

    f32x4 acc[2][2];
#pragma unroll
    for (int m = 0; m < 2; ++m)
#pragma unroll
        for (int ns = 0; ns < 2; ++ns) acc[m][ns] = f32x4{0.f, 0.f, 0.f, 0.f};
#pragma unroll
    for (int cb = 0; cb < 2; ++cb) {
        bf16x8 a0 = *(const bf16x8*)(wgbl + (((wid * 2 + 0) * 2 + cb) * 64 + lane) * 8);
        bf16x8 a1 = *(const bf16x8*)(wgbl + (((wid * 2 + 1) * 2 + cb) * 64 + lane) * 8);
#pragma unroll
        for (int ns = 0; ns < 2; ++ns) {
            int r = ns * 16 + l15;
            int chunk = (cb * 4 + l4) ^ (r & 7);
            bf16x8 bv = *(const bf16x8*)(s_xt + r * 64 + chunk * 8);
            acc[0][ns] = __builtin_amdgcn_mfma_f32_16x16x32_bf16(a0, bv, acc[0][ns], 0, 0, 0);
            acc[1][ns] = __builtin_amdgcn_mfma_f32_16x16x32_bf16(a1, bv, acc[1][ns], 0, 0, 0);
        }
    }

    float4 a1v[2], a2v[2];
#pragma unroll
    for (int m = 0; m < 2; ++m) {
        a1v[m] = *reinterpret_cast<const float4*>(ag + wid * 64 + m * 16 + l4 * 4);
        a2v[m] = *reinterpret_cast<const float4*>(ag + wid * 64 + 32 + m * 16 + l4 * 4);
    }
#pragma unroll
    for (int ns = 0; ns < 2; ++ns) {
        int r = ns * 16 + l15;
        if (r < 25) {
            *reinterpret_cast<float4*>(&s_wh[r * 132 + co0 + l4 * 4]) =
                float4{acc[0][ns][0], acc[0][ns][1], acc[0][ns][2], acc[0][ns][3]};
            *reinterpret_cast<float4*>(&s_wh[r * 132 + co0 + 16 + l4 * 4]) =
                float4{acc[1][ns][0], acc[1][ns][1], acc[1][ns][2], acc[1][ns][3]};
        }
        float pe1 = acc[0][ns][0] * a1v[0].x + acc[0][ns][1] * a1v[0].y
                  + acc[0][ns][2] * a1v[0].z + acc[0][ns][3] * a1v[0].w
                  + acc[1][ns][0] * a1v[1].x + acc[1][ns][1] * a1v[1].y
                  + acc[1][ns][2] * a1v[1].z + acc[1][ns][3] * a1v[1].w;
        float pe2 = acc[0][ns][0] * a2v[0].x + acc[0][ns][1] * a2v[0].y
                  + acc[0][ns][2] * a2v[0].z + acc[0][ns][3] * a2v[0].w
                  + acc[1][ns][0] * a2v[1].x + acc[1][ns][1] * a2v[1].y
                  + acc[1][ns][2] * a2v[1].z + acc[1][ns][3] * a2v[1].w;
        pe1 += __shfl_xor(pe1, 16); pe1 += __shfl_xor(pe1, 32);
        pe2 += __shfl_xor(pe2, 16); pe2 += __shfl_xor(pe2, 32);
        if (l4 == 0 && r < 25) { s_e1[r * 4 + wid] = pe1; s_e2[r * 4 + wid] = pe2; }
    }
    __syncthreads();

    if (tid < 100) {
        int h = tid / 25, i = tid - h * 25;
        float ei = s_e1[i * 4 + h];
        float ev[25];
        float mx = -3.4e38f;
#pragma unroll
        for (int j = 0; j < 25; j++) {
            float e = ei + s_e2[j * 4 + h];
            e = e > 0.f ? e : 0.2f * e;
            e = (s_adj[i * 25 + j] > 0.f) ? e : -9.0e15f;
            ev[j] = e;
            mx = fmaxf(mx, e);
        }
        float sum = 0.f;
#pragma unroll
        for (int j = 0; j < 25; j++) { float p = __expf(ev[j] - mx); ev[j] = p; sum += p; }
        float inv = 1.f / sum;
        int row = (h * 25 + i) * 28;
#pragma unroll
        for (int j = 0; j < 25; j++) s_att[row + j] = ev[j] * inv;
        s_att[row + 25] = 0.f; s_att[row + 26] = 0.f; s_att[row + 27] = 0.f;
    }
    __syncthreads();

    int hd = tid & 127, vh = tid >> 7;
    int v0 = vh * 13, nv = vh ? 12 : 13;
    int h = hd >> 5;
    float whr[28];
#pragma unroll
    for (int j = 0; j < 25; ++j) whr[j] = s_wh[j * 132 + hd];
    whr[25] = 0.f; whr[26] = 0.f; whr[27] = 0.f;
    float accp[13];
#pragma unroll
    for (int i = 0; i < 13; i++) accp[i] = 0.f;
#pragma unroll
    for (int i = 0; i < 13; i++) {
        int row = (h * 25 + v0 + i) * 28;
#pragma unroll
        for (int j4 = 0; j4 < 7; ++j4) {
            float4 a4 = *reinterpret_cast<const float4*>(&s_att[row + j4 * 4]);
            accp[i] += a4.x * whr[j4 * 4] + a4.y * whr[j4 * 4 + 1]
                     + a4.z * whr[j4 * 4 + 2] + a4.w * whr[j4 * 4 + 3];
        }
    }

    // epilogue: elu (fast exp) -> bf16 -> xgt; gn1 per-block partials
    float ssum = 0.f, qsum = 0.f;
    for (int i = 0; i < nv; i++) {
        float val = accp[i];
        val = val > 0.f ? val : (__expf(val) - 1.f);
        bf16 bv = (bf16)val;
        xgt[(nb0 + v0 + i) * 128 + hd] = bv;
        float f = (float)bv;
        ssum += f; qsum += f * f;
    }
    s_rs[tid] = ssum; s_rq[tid] = qsum;
    __syncthreads();
    if (tid < 8) {
        float ss = 0.f, qq = 0.f;
#pragma unroll
        for (int k = 0; k < 16; ++k) {
            int ch = tid * 16 + k;
            ss += s_rs[ch] + s_rs[ch + 128];
            qq += s_rq[ch] + s_rq[ch + 128];
        }
        float* pp = p1 + ((long long)(b * 256 + tile)) * 16;
        pp[tid] = ss;
        pp[8 + tid] = qq;
    }
}

// ---------------- conv body (round-15 tiling: 32co x 128n waves) ----------------
template <int K>
__device__ __forceinline__ void conv_body(bf16* __restrict__ s_h,
                                          float* __restrict__ s_sc, float* __restrict__ s_bc,
                                          float* __restrict__ s_ps, float* __restrict__ s_pq,
                                          const bf16* __restrict__ xgt,
                                          const bf16* __restrict__ wr,
                                          const float* __restrict__ bb,
                                          const float* __restrict__ g1,
                                          const float* __restrict__ b1,
                                          const float* __restrict__ stats1,
                                          bf16* __restrict__ y,
                                          float* __restrict__ p2,
                                          int tile, int b, int tid) {
    constexpr int P = (K - 1) / 2;
    constexpr int ROWS = 128 + (K - 1) * 25;
    constexpr int NCH = ROWS * 16;
    constexpr int ITERS = (NCH + 255) / 256;

    int n0 = tile * 128;
    if (tid < 128) {
        int g = tid >> 4;
        float mu = stats1[b * 8 + g], rs = stats1[256 + b * 8 + g];
        float sc = rs * g1[tid];
        s_sc[tid] = sc;
        s_bc[tid] = b1[tid] - mu * sc;
    }
    __syncthreads();

    int ch = tid & 15;
    float sc8[8], bc8[8];
#pragma unroll
    for (int j = 0; j < 8; ++j) { sc8[j] = s_sc[ch * 8 + j]; bc8[j] = s_bc[ch * 8 + j]; }

    int nb = b * NTV;
    for (int it = 0; it < ITERS; ++it) {
        int flat = it * 256 + tid;
        if (flat < NCH) {
            int r = flat >> 4;
            int n = n0 - P * 25 + r;
            uint4 v = {0u, 0u, 0u, 0u};
            if ((unsigned)n < (unsigned)NTV)
                v = *reinterpret_cast<const uint4*>(xgt + ((long long)(nb + n)) * 128 + ch * 8);
            unsigned w[4] = {v.x, v.y, v.z, v.w};
            uint4 o;
            unsigned* op = &o.x;
#pragma unroll
            for (int p = 0; p < 4; ++p) {
                float f0 = fmaxf(bflo(w[p]) * sc8[2 * p] + bc8[2 * p], 0.f);
                float f1 = fmaxf(bfhi(w[p]) * sc8[2 * p + 1] + bc8[2 * p + 1], 0.f);
                op[p] = packbf2(f0, f1);
            }
            *reinterpret_cast<uint4*>(s_h + r * 128 + (ch ^ (r & 15)) * 8) = o;
        }
    }
    __syncthreads();

    int wid = tid >> 6, lane = tid & 63, l15 = lane & 15, l4 = lane >> 4;
    int co0 = wid * 32;
    f32x4 acc[2][8];
#pragma unroll
    for (int m = 0; m < 2; ++m)
#pragma unroll
        for (int ns = 0; ns < 8; ++ns) acc[m][ns] = f32x4{0.f, 0.f, 0.f, 0.f};

    const bf16* wrA = wr + lane * 8;   // lane-major A
    for (int dt = 0; dt < K; ++dt) {
#pragma unroll
        for (int cb = 0; cb < 4; ++cb) {
            bf16x8 a0 = *(const bf16x8*)(wrA + (((wid * 2 + 0) * K + dt) * 4 + cb) * 512);
            bf16x8 a1 = *(const bf16x8*)(wrA + (((wid * 2 + 1) * K + dt) * 4 + cb) * 512);
#pragma unroll
            for (int ns = 0; ns < 8; ++ns) {
                int r = ns * 16 + l15 + dt * 25;
                int chunk = (cb * 4 + l4) ^ (r & 15);
                bf16x8 bv = *(const bf16x8*)(s_h + r * 128 + chunk * 8);
                acc[0][ns] = __builtin_amdgcn_mfma_f32_16x16x32_bf16(a0, bv, acc[0][ns], 0, 0, 0);
                acc[1][ns] = __builtin_amdgcn_mfma_f32_16x16x32_bf16(a1, bv, acc[1][ns], 0, 0, 0);
            }
        }
    }
    __syncthreads();   // s_h -> s_y reuse

    bf16* sy = s_h;
    float bias[2][4];
#pragma unroll
    for (int m = 0; m < 2; ++m)
#pragma unroll
        for (int rr = 0; rr < 4; ++rr) bias[m][rr] = bb[co0 + m * 16 + l4 * 4 + rr];
    float ssum[2] = {0.f, 0.f}, qsum[2] = {0.f, 0.f};
#pragma unroll
    for (int m = 0; m < 2; ++m)
#pragma unroll
        for (int ns = 0; ns < 8; ++ns) {
            int nl = ns * 16 + l15;
            uint2 pk;
            pk.x = packbf2(acc[m][ns][0] + bias[m][0], acc[m][ns][1] + bias[m][1]);
            pk.y = packbf2(acc[m][ns][2] + bias[m][2], acc[m][ns][3] + bias[m][3]);
            float f0 = bflo(pk.x), f1 = bfhi(pk.x), f2 = bflo(pk.y), f3 = bfhi(pk.y);
            ssum[m] += f0 + f1 + f2 + f3;
            qsum[m] += f0 * f0 + f1 * f1 + f2 * f2 + f3 * f3;
            *reinterpret_cast<uint2*>(sy + nl * 136 + co0 + m * 16 + l4 * 4) = pk;
        }
#pragma unroll
    for (int m = 0; m < 2; ++m) {
        float s = ssum[m], q = qsum[m];
#pragma unroll
        for (int off = 32; off > 0; off >>= 1) { s += __shfl_xor(s, off); q += __shfl_xor(q, off); }
        if (lane == 0) { s_ps[wid * 2 + m] = s; s_pq[wid * 2 + m] = q; }
    }
    __syncthreads();
    if (tid < 8) {
        float* pp = p2 + ((long long)(b * 50 + tile)) * 16;
        pp[tid] = s_ps[tid];
        pp[8 + tid] = s_pq[tid];
    }
#pragma unroll
    for (int it = 0; it < 8; ++it) {
        int flat = it * 256 + tid;
        int nl = flat >> 4, c2 = flat & 15;
        uint4 v = *reinterpret_cast<const uint4*>(sy + nl * 136 + c2 * 8);
        *reinterpret_cast<uint4*>(y + ((long long)(nb + n0 + nl)) * 128 + c2 * 8) = v;
    }
}

// ---------------- merged conv launch: 1D grid, XCD-swizzled, branch-interleaved ----------------
// flat grid 4800 = 3 branches x 50 tiles x 32 batches; 4800 % 8 == 0 -> cpx = 600.
// swz = (bid&7)*600 + (bid>>3): each XCD gets a contiguous 600-run; neighbor tiles
// (swz +- 3, same b/branch, halo-sharing) stay on the same XCD's L2; branch = swz%3
// interleaves K=3/5/7 so the dispatch tail is mixed, not all-K7.
__global__ __launch_bounds__(256) void conv_all_kernel(const bf16* __restrict__ xgt,
                                                       const bf16* __restrict__ wr3,
                                                       const bf16* __restrict__ wr5,
                                                       const bf16* __restrict__ wr7,
                                                       const float* __restrict__ bb3,
                                                       const float* __restrict__ bb5,
                                                       const float* __restrict__ bb7,
                                                       const float* __restrict__ g13,
                                                       const float* __restrict__ g15,
                                                       const float* __restrict__ g17,
                                                       const float* __restrict__ b13,
                                                       const float* __restrict__ b15,
                                                       const float* __restrict__ b17,
                                                       const float* __restrict__ stats1,
                                                       bf16* __restrict__ y0,
                                                       bf16* __restrict__ y1,
                                                       bf16* __restrict__ y2,
                                                       float* __restrict__ p2) {
    __shared__ bf16 s_h[278 * 128];     // sized for K=7 window
    __shared__ float s_sc[128], s_bc[128];
    __shared__ float s_ps[8], s_pq[8];
    int bid = blockIdx.x;
    int swz = (bid & 7) * 600 + (bid >> 3);
    int branch = swz % 3;
    int t2 = swz / 3;
    int tile = t2 % 50;
    int b = t2 / 50;
    int tid = threadIdx.x;
    switch (branch) {
        case 0:
            conv_body<3>(s_h, s_sc, s_bc, s_ps, s_pq, xgt, wr3, bb3, g13, b13,
                         stats1, y0, p2, tile, b, tid);
            break;
        case 1:
            conv_body<5>(s_h, s_sc, s_bc, s_ps, s_pq, xgt, wr5, bb5, g15, b15,
                         stats1, y1, p2 + 25600, tile, b, tid);
            break;
        default:
            conv_body<7>(s_h, s_sc, s_bc, s_ps, s_pq, xgt, wr7, bb7, g17, b17,
                         stats1, y2, p2 + 51200, tile, b, tid);
            break;
    }
}

// ---------------- fold gn2 into fusion weights: grid (32 b, 8 cb_co) ----------------
__global__ __launch_bounds__(256) void fold_kernel(const float* __restrict__ fus_w, const float* __restrict__ fus_b,
                                                   const float* __restrict__ res_w, const float* __restrict__ res_b,
                                                   const float* __restrict__ g20, const float* __restrict__ b20,
                                                   const float* __restrict__ g21, const float* __restrict__ b21,
                                                   const float* __restrict__ g22, const float* __restrict__ b22,
                                                   const float* __restrict__ st0, const float* __restrict__ st1,
                                                   const float* __restrict__ st2,
                                                   bf16* __restrict__ Abig, float* __restrict__ biasb) {
    __shared__ float s_sc[384], s_bc[384];
    int b = blockIdx.x, cb_co = blockIdx.y, tid = threadIdx.x;
    int co0 = cb_co * 16;
    for (int o = tid; o < 384; o += 256) {
        int k = o >> 7, cc = o & 127, g = cc >> 4;
        const float* st = (k == 0) ? st0 : (k == 1) ? st1 : st2;
        const float* gg = (k == 0) ? g20 : (k == 1) ? g21 : g22;
        const float* b2 = (k == 0) ? b20 : (k == 1) ? b21 : b22;
        float mu = st[b * 8 + g], rs = st[256 + b * 8 + g];
        float sc = rs * gg[cc];
        s_sc[o] = sc;
        s_bc[o] = b2[cc] - mu * sc;
    }
    __syncthreads();

    bf16* abase = Abig + ((long long)(b * 8 + cb_co)) * 14 * 512;
#pragma unroll 1
    for (int it = 0; it < 28; ++it) {
        int o = it * 256 + tid;
        int e = o & 7;
        int lane = (o >> 3) & 63;
        int ks = o >> 9;
        int l15 = lane & 15, l4 = lane >> 4;
        int co = co0 + l15;
        int j = ks * 32 + l4 * 8 + e;
        float val = (j < 384) ? fus_w[co * 384 + j] * s_sc[j] : res_w[co * 64 + (j - 384)];
        abase[o] = (bf16)val;
    }

    int co_l = tid >> 4, part = tid & 15;
    int co = co0 + co_l;
    float s = 0.f;
#pragma unroll
    for (int k = 0; k < 24; ++k) {
        int j = part + k * 16;
        s += fus_w[co * 384 + j] * s_bc[j];
    }
#pragma unroll
    for (int off = 1; off < 16; off <<= 1) s += __shfl_xor(s, off);
    if (part == 0)
        biasb[b * 128 + co] = fus_b[co] + res_b[co] + s;
}

// ---------------- fused output GEMM (32-row tiles) + gn3 per-block partials ----------------
__global__ __launch_bounds__(256) void fuse_mfma_kernel(const bf16* __restrict__ y0, const bf16* __restrict__ y1,
                                                        const bf16* __restrict__ y2, const bf16* __restrict__ xt,
                                                        const bf16* __restrict__ Abig, const float* __restrict__ biasb,
                                                        float* __restrict__ accf, float* __restrict__ p3) {
    __shared__ __align__(16) bf16 s_b[32 * 448];
    __shared__ float s_ps[8], s_pq[8];
    int tile = blockIdx.x, b = blockIdx.y, tid = threadIdx.x;
    int n0 = tile * 32;

    int c = tid % 56;
    int roff = tid / 56;
    bool act = tid < 224;
    const bf16* src;
    int stride;
    if (c < 48) {
        src = (c < 16 ? y0 : (c < 32 ? y1 : y2)) + (c & 15) * 8;
        stride = 128;
    } else {
        src = xt + (c - 48) * 8;
        stride = 64;
    }
    src += (long long)(b * NTV + n0) * stride;
    if (act) {
#pragma unroll
        for (int it = 0; it < 8; ++it) {
            int r = it * 4 + roff;
            uint4 v = *reinterpret_cast<const uint4*>(src + (long long)r * stride);
            *reinterpret_cast<uint4*>(s_b + r * 448 + (c ^ (r & 7)) * 8) = v;
        }
    }
    __syncthreads();

    int wid = tid >> 6, lane = tid & 63, l15 = lane & 15, l4 = lane >> 4;
    int co0 = wid * 32;
    f32x4 acc[2][2];
#pragma unroll
    for (int m = 0; m < 2; ++m)
#pragma unroll
        for (int ns = 0; ns < 2; ++ns) acc[m][ns] = f32x4{0.f, 0.f, 0.f, 0.f};

    const bf16* abase = Abig + (((long long)(b * 8 + wid * 2)) * 14 * 64 + lane) * 8;
#pragma unroll
    for (int ks = 0; ks < 14; ++ks) {
        bf16x8 a0 = *(const bf16x8*)(abase + ks * 512);
        bf16x8 a1 = *(const bf16x8*)(abase + 14 * 512 + ks * 512);
        int ci = ks * 4 + l4;
#pragma unroll
        for (int ns = 0; ns < 2; ++ns) {
            int r = ns * 16 + l15;
            bf16x8 bv = *(const bf16x8*)(s_b + r * 448 + (ci ^ (r & 7)) * 8);
            acc[0][ns] = __builtin_amdgcn_mfma_f32_16x16x32_bf16(a0, bv, acc[0][ns], 0, 0, 0);
            acc[1][ns] = __builtin_amdgcn_mfma_f32_16x16x32_bf16(a1, bv, acc[1][ns], 0, 0, 0);
        }
    }

    float bias[2][4];
#pragma unroll
    for (int m = 0; m < 2; ++m)
#pragma unroll
        for (int rr = 0; rr < 4; ++rr) bias[m][rr] = biasb[b * 128 + co0 + m * 16 + l4 * 4 + rr];

    __syncthreads();
    float* s_yf = reinterpret_cast<float*>(s_b);
    float ssum[2] = {0.f, 0.f}, qsum[2] = {0.f, 0.f};
#pragma unroll
    for (int m = 0; m < 2; ++m)
#pragma unroll
        for (int ns = 0; ns < 2; ++ns) {
            int nl = ns * 16 + l15;
            float4 val;
            val.x = acc[m][ns][0] + bias[m][0];
            val.y = acc[m][ns][1] + bias[m][1];
            val.z = acc[m][ns][2] + bias[m][2];
            val.w = acc[m][ns][3] + bias[m][3];
            float r0 = fmaxf(val.x, 0.f), r1 = fmaxf(val.y, 0.f);
            float r2 = fmaxf(val.z, 0.f), r3 = fmaxf(val.w, 0.f);
            ssum[m] += r0 + r1 + r2 + r3;
            qsum[m] += r0 * r0 + r1 * r1 + r2 * r2 + r3 * r3;
            *reinterpret_cast<float4*>(s_yf + nl * 136 + co0 + m * 16 + l4 * 4) = val;
        }
#pragma unroll
    for (int m = 0; m < 2; ++m) {
        float s = ssum[m], q = qsum[m];
#pragma unroll
        for (int off = 32; off > 0; off >>= 1) { s += __shfl_xor(s, off); q += __shfl_xor(q, off); }
        if (lane == 0) { s_ps[wid * 2 + m] = s; s_pq[wid * 2 + m] = q; }
    }
    __syncthreads();
    if (tid < 8) {
        float* pp = p3 + ((long long)(b * 200 + tile)) * 16;
        pp[tid] = s_ps[tid];
        pp[8 + tid] = s_pq[tid];
    }
#pragma unroll
    for (int it = 0; it < 4; ++it) {
        int flat = it * 256 + tid;
        int nl = flat >> 5, cq = flat & 31;
        float4 v = *reinterpret_cast<const float4*>(s_yf + nl * 136 + cq * 4);
        *reinterpret_cast<float4*>(accf + ((long long)(b * NTV + n0 + nl)) * 128 + cq * 4) = v;
    }
}

// ---------------- final: out = gn3(relu(acc fp32)), transpose to [b][c][n] fp32 ----------------
__global__ __launch_bounds__(256) void final_kernel(const float* __restrict__ accf,
                                                    const float* __restrict__ stats3,
                                                    const float* __restrict__ ng,
                                                    const float* __restrict__ nb,
                                                    float* __restrict__ out) {
    __shared__ float s_o[128 * 72];
    __shared__ float s_sc[128], s_bc[128];
    int tile = blockIdx.x, b = blockIdx.y, tid = threadIdx.x;
    int n0 = tile * 64;
    if (tid < 128) {
        int g = tid >> 4;
        float mu = stats3[b * 8 + g], rs = stats3[256 + b * 8 + g];
        float sv = rs * ng[tid];
        s_sc[tid] = sv;
        s_bc[tid] = nb[tid] - mu * sv;
    }
    __syncthreads();
#pragma unroll
    for (int it = 0; it < 8; ++it) {
        int flat = it * 256 + tid;
        int r = flat >> 5, cq = flat & 31;
        float4 v = *reinterpret_cast<const float4*>(accf + ((long long)(b * NTV + n0 + r)) * 128 + cq * 4);
        float f[4] = {v.x, v.y, v.z, v.w};
#pragma unroll
        for (int p = 0; p < 4; ++p) {
            int ci = cq * 4 + p;
            s_o[ci * 72 + r] = fmaxf(f[p], 0.f) * s_sc[ci] + s_bc[ci];
        }
    }
    __syncthreads();
#pragma unroll
    for (int it = 0; it < 8; ++it) {
        int flat = it * 256 + tid;
        int ci = flat >> 4, q = flat & 15;
        float4 v = *reinterpret_cast<const float4*>(s_o + ci * 72 + q * 4);
        *reinterpret_cast<float4*>(out + ((long long)(b * 128 + ci)) * NTV + n0 + q * 4) = v;
    }
}

extern "C" void kernel_launch(void* const* d_in, const int* in_sizes, int n_in,
                              void* d_out, int out_size, void* d_ws, size_t ws_size,
                              hipStream_t stream) {
    const float* x      = (const float*)d_in[0];
    const float* adj    = (const float*)d_in[1];
    const float* w_gat  = (const float*)d_in[2];
    const float* a_gat  = (const float*)d_in[3];
    const float* fus_w  = (const float*)d_in[4];
    const float* fus_b  = (const float*)d_in[5];
    const float* res_w  = (const float*)d_in[6];
    const float* res_b  = (const float*)d_in[7];
    const float* norm_g = (const float*)d_in[8];
    const float* norm_b = (const float*)d_in[9];
    const float* tg1[3], *tb1[3], *tw[3], *tbb[3], *tg2[3], *tb2[3];
    for (int i = 0; i < 3; i++) {
        tg1[i] = (const float*)d_in[10 + 6 * i + 0];
        tb1[i] = (const float*)d_in[10 + 6 * i + 1];
        tw[i]  = (const float*)d_in[10 + 6 * i + 2];
        tbb[i] = (const float*)d_in[10 + 6 * i + 3];
        tg2[i] = (const float*)d_in[10 + 6 * i + 4];
        tb2[i] = (const float*)d_in[10 + 6 * i + 5];
    }

    float* ws = (float*)d_ws;
    float* accf  = ws + ACC_OFF;                    // fp32, aliases xgt/wrb/wgbl (dead by fuse)
    bf16* xgt    = (bf16*)(ws + XGT_OFF);
    bf16* wrb[3] = { (bf16*)(ws + WRB3_OFF), (bf16*)(ws + WRB5_OFF), (bf16*)(ws + WRB7_OFF) };
    bf16* wgbl   = (bf16*)(ws + WGB_OFF);
    bf16* yb[3]  = { (bf16*)(ws + Y0_OFF), (bf16*)(ws + Y1_OFF), (bf16*)(ws + Y2_OFF) };
    bf16* xt     = (bf16*)(ws + XT_OFF);
    bf16* Abig   = (bf16*)(ws + ABIG_OFF);
    float* biasb = ws + BIAS_OFF;
    float* S1    = ws + STATS_OFF;
    float* S2    = S1 + 512;
    float* S3    = S1 + 2048;
    float* P1    = ws + P1_OFF;
    float* P2    = ws + P2_OFF;   // 3 x [32][50][16]
    float* P3    = ws + P3_OFF;   // [32][200][16]

    prep_kernel<<<(PREP_TOT + 255) / 256, 256, 0, stream>>>(tw[0], tw[1], tw[2], w_gat,
                                                            wrb[0], wrb[1], wrb[2], wgbl);

    dim3 g64(100, 32), g32f(200, 32), ggat(256, 32);

    // fused GAT (reads x; emits xgt, xt, gn1 partials)
    gat_fused_kernel<<<ggat, 256, 0, stream>>>(x, wgbl, adj, a_gat, xgt, xt, P1);
    reduce_stats_kernel<<<dim3(32, 1), 256, 0, stream>>>(P1, 256, S1, 0, 0);

    // all three convs, 1D XCD-swizzled branch-interleaved grid
    conv_all_kernel<<<4800, 256, 0, stream>>>(xgt, wrb[0], wrb[1], wrb[2],
                                              tbb[0], tbb[1], tbb[2],
                                              tg1[0], tg1[1], tg1[2],
                                              tb1[0], tb1[1], tb1[2],
                                              S1, yb[0], yb[1], yb[2], P2);
    reduce_stats_kernel<<<dim3(32, 3), 256, 0, stream>>>(P2, 50, S2, 25600, 512);

    fold_kernel<<<dim3(32, 8), 256, 0, stream>>>(fus_w, fus_b, res_w, res_b,
                                                 tg2[0], tb2[0], tg2[1], tb2[1], tg2[2], tb2[2],
                                                 S2, S2 + 512, S2 + 1024, Abig, biasb);

    // fuse overwrites the xgt/wrb/wgbl region with fp32 acc; writes gn3 partials
    fuse_mfma_kernel<<<g32f, 256, 0, stream>>>(yb[0], yb[1], yb[2], xt, Abig, biasb, accf, P3);
    reduce_stats_kernel<<<dim3(32, 1), 256, 0, stream>>>(P3, 200, S3, 0, 0);

    final_kernel<<<g64, 256, 0, stream>>>(accf, S3, norm_g, norm_b, (float*)d_out);
}